// Round 7
// baseline (111.605 us; speedup 1.0000x reference)
//
#include <hip/hip_runtime.h>
#include <math.h>

#define NBANDS 2049
#define NF 4096      // real frame size
#define NC 2048      // complex FFT size (rfft via packed complex)
#define BUF 1024     // input samples per batch row
#define THREADS 512
#define R2C 0.70710678118654752f

// 8B-granularity LDS swizzle on float2 index: p = i ^ h(bits 5..9 of i),
// h -> bits 1..3. Bijective; preserves bit0 (pair adjacency & 16B align);
// verified <=2-way banking for all stage/unpack patterns.
__device__ __forceinline__ int SW2(int i) {
  const int h = ((((i >> 6) ^ (i >> 7)) & 1) << 1) |
                ((((i >> 5) ^ (i >> 8)) & 1) << 2) |
                ((((i >> 5) ^ (i >> 9)) & 1) << 3);
  return i ^ h;
}

// digit-reversed position after 5 radix-4 stages (final radix-2 folded out);
// output is always even (bit0 never set)
__device__ __forceinline__ int posrev10(int j) {
  return ((j & 3) << 9) | (((j >> 2) & 3) << 7) | (((j >> 4) & 3) << 5) |
         (((j >> 6) & 3) << 3) | (((j >> 8) & 3) << 1);
}

struct Smem {
  float xs[BUF];                    // 4 KB
  alignas(16) float2 zA[NC];        // 16 KB (interleaved complex)
  alignas(16) float2 zB[NC];        // 16 KB
  float ob[4 * NBANDS];             // 32 KB output-column staging
};                                  // ~68.5 KB -> 2 blocks/CU

struct State {
  float2 W[5];                   // per-thread stage twiddles
  float2 Ub;                     // exp(-pi*i*tid/2048)
  float2 U1;                     // Ub * exp(-i*pi/4)
  float so;                      // sin(pi*(2*tid+1)/2048) (odd window base)
  float s1a[5], s1b[5];          // running mins after lvl1 (two subtrees)
  float s2a[5], s2b[5];          // running mins after lvl2 (two live nodes)
};

__device__ __forceinline__ float2 cmul(float2 a, float2 b) {
  return make_float2(a.x * b.x - a.y * b.y, a.x * b.y + a.y * b.x);
}

// Chebyshev cos-doubling: cos(t) -> cos(2^L * t)
template <int L>
__device__ __forceinline__ float cheb(float c) {
  #pragma unroll
  for (int i = 0; i < L; ++i) c = 2.0f * c * c - 1.0f;
  return c;
}

// Fused pack + pruned first radix-4 stage (span 512): only tap3 nonzero.
// y = {d, i*d*W, -d*W^2, -i*d*W^3}, d = windowed sample pair from xs.
template <int L>
__device__ __forceinline__ void fused_s1(float2* __restrict__ z,
                                         const Smem& sm, const State& st, int off) {
  const int n = threadIdx.x;
  constexpr int M = NF >> L;
  constexpr float ws = (float)(1 << L) * (0.5f / 1024.0f);
  const int lo = 512 - (min(off, M) >> 1);
  float dr = 0.0f, di = 0.0f;
  if (n >= lo) {
    const int idx = 2 * n + off - 1024;          // even, in [0, off)
    const float2 xv = *(const float2*)&sm.xs[idx];
    const float cE = cheb<L>(-st.W[0].y);        // cos at even sample
    const float cO = cheb<L>(st.so);             // cos at odd sample
    dr = ws * (1.0f - cE) * xv.x;
    di = ws * (1.0f - cO) * xv.y;
  }
  const float2 W = st.W[0];
  const float2 W2 = make_float2(W.x * W.x - W.y * W.y, 2.0f * W.x * W.y);
  const float2 W3 = cmul(W, W2);
  z[SW2(n)]        = make_float2(dr, di);
  z[SW2(n + 512)]  = make_float2(-di * W.x - dr * W.y, -di * W.y + dr * W.x);   // (i d) W
  z[SW2(n + 1024)] = make_float2(-(dr * W2.x - di * W2.y), -(dr * W2.y + di * W2.x)); // -d W^2
  z[SW2(n + 1536)] = make_float2(di * W3.x + dr * W3.y, di * W3.y - dr * W3.x); // (-i d) W^3
}

__device__ __forceinline__ void bfly4(float2* __restrict__ z,
                                      int i0, int i1, int i2, int i3,
                                      float2 W, float2 W2, float2 W3) {
  const float2 a = z[i0], b = z[i1], c = z[i2], d = z[i3];
  const float t0r = a.x + c.x, t0i = a.y + c.y;
  const float t1r = a.x - c.x, t1i = a.y - c.y;
  const float t2r = b.x + d.x, t2i = b.y + d.y;
  const float t3r = b.x - d.x, t3i = b.y - d.y;
  z[i0] = make_float2(t0r + t2r, t0i + t2i);
  const float y1r = t1r + t3i, y1i = t1i - t3r;            // (t1 - i*t3)
  z[i1] = make_float2(y1r * W.x - y1i * W.y, y1r * W.y + y1i * W.x);
  const float y2r = t0r - t2r, y2i = t0i - t2i;
  z[i2] = make_float2(y2r * W2.x - y2i * W2.y, y2r * W2.y + y2i * W2.x);
  const float y3r = t1r - t3i, y3i = t1i + t3r;            // (t1 + i*t3)
  z[i3] = make_float2(y3r * W3.x - y3i * W3.y, y3r * W3.y + y3i * W3.x);
}

template <int LM, bool HASB>
__device__ __forceinline__ void radix4p(Smem& sm, float2 W) {
  const int j = threadIdx.x;
  const int m = 1 << LM;
  const int base = ((j >> LM) << (LM + 2)) | (j & (m - 1));
  const int i0 = SW2(base), i1 = SW2(base + m), i2 = SW2(base + 2 * m), i3 = SW2(base + 3 * m);
  const float2 W2 = make_float2(W.x * W.x - W.y * W.y, 2.0f * W.x * W.y);
  const float2 W3 = cmul(W, W2);
  bfly4(sm.zA, i0, i1, i2, i3, W, W2, W3);
  if constexpr (HASB) bfly4(sm.zB, i0, i1, i2, i3, W, W2, W3);
}

// Shared-read pair unpack: one b128 grabs D[e] and D[e^1] (adjacent after SW2).
// p(kp) = |E + U*O|^2, p(2048-kp) = |E - U*O|^2.
__device__ __forceinline__ void pair_powers(const float2* __restrict__ z,
                                            int kp, float2 U, float& pp, float& pm) {
  const int k1 = kp & (NC - 1);
  const int k2 = (NC - kp) & (NC - 1);
  const int q1 = SW2(posrev10(k1 & 1023));   // even
  const int q2 = SW2(posrev10(k2 & 1023));   // even
  const float s1 = (k1 & 1024) ? -1.0f : 1.0f;
  const float s2 = (k2 & 1024) ? -1.0f : 1.0f;
  const float4 v1 = *(const float4*)&z[q1];
  const float4 v2 = *(const float4*)&z[q2];
  const float zkr = v1.x + s1 * v1.z;
  const float zki = v1.y + s1 * v1.w;
  const float zmr = v2.x + s2 * v2.z;
  const float zmi = v2.y + s2 * v2.w;
  const float Ex = 0.5f * (zkr + zmr), Ey = 0.5f * (zki - zmi);
  const float Ox = 0.5f * (zki + zmi), Oy = -0.5f * (zkr - zmr);
  const float Vx = U.x * Ox - U.y * Oy, Vy = U.x * Oy + U.y * Ox;
  const float ax = Ex + Vx, ay = Ey + Vy;
  const float bx = Ex - Vx, by = Ey - Vy;
  pp = ax * ax + ay * ay;
  pm = bx * bx + by * by;
}

// ACT: 0 s1a=min(p,1e6); 1 s1b=min(p,1e6); 2 lvl0 fold into s1a&s1b;
//      3 s2a=min(s1a,p); 4 s2b=min(s1a,p); 5 s2a=min(s1b,p); 6 s2b=min(s1b,p);
//      7 ob[COL]=dB(min(s2a,p)); 8 ob[COL]=dB(min(s2b,p))
template <int ACT, int COL, int SLOT>
__device__ __forceinline__ void act(State& st, Smem& sm, int bin, float p) {
  if constexpr (ACT == 0)      st.s1a[SLOT] = fminf(p, 1.0e6f);
  else if constexpr (ACT == 1) st.s1b[SLOT] = fminf(p, 1.0e6f);
  else if constexpr (ACT == 2) { st.s1a[SLOT] = fminf(st.s1a[SLOT], p); st.s1b[SLOT] = fminf(st.s1b[SLOT], p); }
  else if constexpr (ACT == 3) st.s2a[SLOT] = fminf(st.s1a[SLOT], p);
  else if constexpr (ACT == 4) st.s2b[SLOT] = fminf(st.s1a[SLOT], p);
  else if constexpr (ACT == 5) st.s2a[SLOT] = fminf(st.s1b[SLOT], p);
  else if constexpr (ACT == 6) st.s2b[SLOT] = fminf(st.s1b[SLOT], p);
  else if constexpr (ACT == 7) sm.ob[COL * NBANDS + bin] = 10.0f * log10f(fmaxf(fminf(st.s2a[SLOT], p), 1.0e-10f));
  else                         sm.ob[COL * NBANDS + bin] = 10.0f * log10f(fmaxf(fminf(st.s2b[SLOT], p), 1.0e-10f));
}

template <int ACT, int COL>
__device__ __forceinline__ void unpack_frame(const float2* __restrict__ z,
                                             State& st, Smem& sm) {
  const int t = threadIdx.x;
  float pp, pm;
  pair_powers(z, t, st.Ub, pp, pm);
  act<ACT, COL, 0>(st, sm, t, pp);
  act<ACT, COL, 1>(st, sm, 2048 - t, pm);
  pair_powers(z, 512 + t, st.U1, pp, pm);
  act<ACT, COL, 2>(st, sm, 512 + t, pp);
  act<ACT, COL, 3>(st, sm, 1536 - t, pm);
  if (t == 0) {
    // bin 1024: Z[1024] = D[0] - D[1]
    const float4 v = *(const float4*)&z[0];
    const float zr = v.x - v.z;
    const float zi = v.y - v.w;
    act<ACT, COL, 4>(st, sm, 1024, zr * zr + zi * zi);
  }
}

// One pass = two windowed frames, FFT'd together, unpacked, min-chain applied.
template <int LA, int ACTA, int COLA, int LB, int ACTB, int COLB, bool HASB>
__device__ __forceinline__ void pass(Smem& sm, State& st, int offA, int offB) {
  __syncthreads();                          // prior pass done reading z arrays
  fused_s1<LA>(sm.zA, sm, st, offA);
  if constexpr (HASB) fused_s1<LB>(sm.zB, sm, st, offB);
  __syncthreads(); radix4p<7, HASB>(sm, st.W[1]);
  __syncthreads(); radix4p<5, HASB>(sm, st.W[2]);
  __syncthreads(); radix4p<3, HASB>(sm, st.W[3]);
  __syncthreads(); radix4p<1, HASB>(sm, st.W[4]);
  __syncthreads();
  unpack_frame<ACTA, COLA>(sm.zA, st, sm);
  if constexpr (HASB) unpack_frame<ACTB, COLB>(sm.zB, st, sm);
}

template <int T0>
__device__ __forceinline__ void store_cols(Smem& sm, float* __restrict__ outb) {
  __syncthreads();                          // ob written by other threads
  const int tid = threadIdx.x;
  #pragma unroll
  for (int it = 0; it < 5; ++it) {
    if (it < 4 || tid == 0) {
      const int band = tid + it * THREADS;
      float4 v = make_float4(sm.ob[band], sm.ob[NBANDS + band],
                             sm.ob[2 * NBANDS + band], sm.ob[3 * NBANDS + band]);
      *(float4*)&outb[(size_t)band * 8 + T0] = v;
    }
  }
}

__global__ __launch_bounds__(THREADS, 2) void spec_kernel(const float* __restrict__ x,
                                                          float* __restrict__ out) {
  __shared__ Smem sm;
  State st;
  const int tid = threadIdx.x;
  const int b = blockIdx.x;
  const float* xb = x + (size_t)b * BUF;
  #pragma unroll
  for (int i = tid; i < BUF; i += THREADS) sm.xs[i] = xb[i];
  {
    float sn, cs;
    sincospif((float)tid * (1.0f / 1024.0f), &sn, &cs);         st.W[0] = make_float2(cs, -sn);
    sincospif((float)(tid & 127) * (1.0f / 256.0f), &sn, &cs);  st.W[1] = make_float2(cs, -sn);
    sincospif((float)(tid & 31) * (1.0f / 64.0f), &sn, &cs);    st.W[2] = make_float2(cs, -sn);
    sincospif((float)(tid & 7) * (1.0f / 16.0f), &sn, &cs);     st.W[3] = make_float2(cs, -sn);
    st.W[4] = (tid & 1) ? make_float2(R2C, -R2C) : make_float2(1.0f, 0.0f);
    sincospif((float)tid * (1.0f / 2048.0f), &sn, &cs);         st.Ub = make_float2(cs, -sn);
    st.U1 = cmul(st.Ub, make_float2(R2C, -R2C));
    sincospif((float)(2 * tid + 1) * (1.0f / 2048.0f), &sn, &cs); st.so = sn;
  }
  float* outb = out + (size_t)b * (NBANDS * 8);

  // Frames: lvl0 off=1024; lvl1 off=512*(i+1); lvl2 off=256*(i+1); lvl3 off=128*(i+1)
  pass<1, 0, 0,  1, 1, 0, true >(sm, st, 512, 1024);   // s1a=l1_0, s1b=l1_1
  pass<0, 2, 0,  2, 3, 0, true >(sm, st, 1024, 256);   // fold lvl0; s2a=min(s1a,l2_0)
  pass<2, 4, 0,  3, 7, 0, true >(sm, st, 512, 128);    // s2b=min(s1a,l2_1); ob0=dB(s2a,l3_0)
  pass<3, 7, 1,  3, 8, 2, true >(sm, st, 256, 384);    // ob1=dB(s2a,l3_1); ob2=dB(s2b,l3_2)
  pass<3, 8, 3,  2, 5, 0, true >(sm, st, 512, 768);    // ob3=dB(s2b,l3_3); s2a=min(s1b,l2_2)
  store_cols<0>(sm, outb);
  pass<2, 6, 0,  3, 7, 0, true >(sm, st, 1024, 640);   // s2b=min(s1b,l2_3); ob0=dB(s2a,l3_4)
  pass<3, 7, 1,  3, 8, 2, true >(sm, st, 768, 896);    // ob1=dB(s2a,l3_5); ob2=dB(s2b,l3_6)
  pass<3, 8, 3,  0, 0, 0, false>(sm, st, 1024, 0);     // ob3=dB(s2b,l3_7)
  store_cols<4>(sm, outb);
}

extern "C" void kernel_launch(void* const* d_in, const int* in_sizes, int n_in,
                              void* d_out, int out_size, void* d_ws, size_t ws_size,
                              hipStream_t stream) {
  const float* x = (const float*)d_in[0];
  float* out = (float*)d_out;
  const int B = in_sizes[0] / BUF;
  hipLaunchKernelGGL(spec_kernel, dim3(B), dim3(THREADS), 0, stream, x, out);
}

// Round 8
// 100.580 us; speedup vs baseline: 1.1096x; 1.1096x over previous
//
#include <hip/hip_runtime.h>
#include <math.h>

#define NBANDS 2049
#define NF 4096      // real frame size
#define NC 2048      // complex FFT size (rfft via packed complex)
#define BUF 1024     // input samples per batch row
#define THREADS 512
#define R2C 0.70710678118654752f

// LDS bank swizzle: bijective on [0,2048); SW(e^1) == SW(e)^1
__device__ __forceinline__ int SW(int i) { return i ^ (i >> 2) ^ (i >> 6); }

// digit-reversed position after 5 radix-4 stages (final radix-2 folded out);
// output is always even
__device__ __forceinline__ int posrev10(int j) {
  return ((j & 3) << 9) | (((j >> 2) & 3) << 7) | (((j >> 4) & 3) << 5) |
         (((j >> 6) & 3) << 3) | (((j >> 8) & 3) << 1);
}

struct Smem {
  float xs[BUF];                 // 4 KB
  float zreA[NC], zimA[NC];      // 16 KB
  float zreB[NC], zimB[NC];      // 16 KB
};                               // 36.5 KB

struct State {
  float2 W[5];                   // per-thread stage twiddles
  float2 Ub;                     // exp(-pi*i*tid/2048)
  float2 U1;                     // Ub * exp(-i*pi/4)
  float so;                      // sin(pi*(2*tid+1)/2048) (odd window base)
  float s1a[5], s1b[5];          // running mins after lvl1 (two subtrees)
  float s2a[5], s2b[5];          // running mins after lvl2 (two live nodes)
  float o[8][5];                 // dB output columns, all register-resident
};

__device__ __forceinline__ float2 cmul(float2 a, float2 b) {
  return make_float2(a.x * b.x - a.y * b.y, a.x * b.y + a.y * b.x);
}

// Chebyshev cos-doubling: cos(t) -> cos(2^L * t)
template <int L>
__device__ __forceinline__ float cheb(float c) {
  #pragma unroll
  for (int i = 0; i < L; ++i) c = 2.0f * c * c - 1.0f;
  return c;
}

// Fused pack + pruned first radix-4 stage (span 512): only tap3 nonzero.
// y = {d, i*d*W, -d*W^2, -i*d*W^3}, d = windowed sample pair from xs.
template <int L>
__device__ __forceinline__ void fused_s1(float* __restrict__ re, float* __restrict__ im,
                                         const Smem& sm, const State& st, int off) {
  const int n = threadIdx.x;
  constexpr int M = NF >> L;
  constexpr float ws = (float)(1 << L) * (0.5f / 1024.0f);
  const int lo = 512 - (min(off, M) >> 1);
  float dr = 0.0f, di = 0.0f;
  if (n >= lo) {
    const int idx = 2 * n + off - 1024;          // even, in [0, off)
    const float2 xv = *(const float2*)&sm.xs[idx];
    const float cE = cheb<L>(-st.W[0].y);        // cos at even sample
    const float cO = cheb<L>(st.so);             // cos at odd sample
    dr = ws * (1.0f - cE) * xv.x;
    di = ws * (1.0f - cO) * xv.y;
  }
  const float2 W = st.W[0];
  const float2 W2 = make_float2(W.x * W.x - W.y * W.y, 2.0f * W.x * W.y);
  const float2 W3 = cmul(W, W2);
  const int p0 = SW(n), p1 = SW(n + 512), p2 = SW(n + 1024), p3 = SW(n + 1536);
  re[p0] = dr;                       im[p0] = di;
  re[p1] = -di * W.x - dr * W.y;     im[p1] = -di * W.y + dr * W.x;     // (i d) W
  re[p2] = -(dr * W2.x - di * W2.y); im[p2] = -(dr * W2.y + di * W2.x); // -d W^2
  re[p3] =  di * W3.x + dr * W3.y;   im[p3] =  di * W3.y - dr * W3.x;   // (-i d) W^3
}

__device__ __forceinline__ void bfly4(float* __restrict__ re, float* __restrict__ im,
                                      int i0, int i1, int i2, int i3,
                                      float2 W, float2 W2, float2 W3) {
  float ar = re[i0], ai = im[i0];
  float br = re[i1], bi = im[i1];
  float cr = re[i2], ci = im[i2];
  float dr = re[i3], di = im[i3];
  float t0r = ar + cr, t0i = ai + ci;
  float t1r = ar - cr, t1i = ai - ci;
  float t2r = br + dr, t2i = bi + di;
  float t3r = br - dr, t3i = bi - di;
  re[i0] = t0r + t2r; im[i0] = t0i + t2i;
  float y1r = t1r + t3i, y1i = t1i - t3r;                  // (t1 - i*t3)
  re[i1] = y1r * W.x - y1i * W.y;  im[i1] = y1r * W.y + y1i * W.x;
  float y2r = t0r - t2r, y2i = t0i - t2i;
  re[i2] = y2r * W2.x - y2i * W2.y; im[i2] = y2r * W2.y + y2i * W2.x;
  float y3r = t1r - t3i, y3i = t1i + t3r;                  // (t1 + i*t3)
  re[i3] = y3r * W3.x - y3i * W3.y; im[i3] = y3r * W3.y + y3i * W3.x;
}

template <int LM, bool HASB>
__device__ __forceinline__ void radix4p(Smem& sm, float2 W) {
  const int j = threadIdx.x;
  const int m = 1 << LM;
  const int base = ((j >> LM) << (LM + 2)) | (j & (m - 1));
  const int i0 = SW(base), i1 = SW(base + m), i2 = SW(base + 2 * m), i3 = SW(base + 3 * m);
  float2 W2 = make_float2(W.x * W.x - W.y * W.y, 2.0f * W.x * W.y);
  float2 W3 = cmul(W, W2);
  bfly4(sm.zreA, sm.zimA, i0, i1, i2, i3, W, W2, W3);
  if constexpr (HASB) bfly4(sm.zreB, sm.zimB, i0, i1, i2, i3, W, W2, W3);
}

// Shared-read pair unpack: bins kp and 2048-kp read the same Z values.
// p(kp) = |E + U*O|^2, p(2048-kp) = |E - U*O|^2.
__device__ __forceinline__ void pair_powers(const float* __restrict__ re,
                                            const float* __restrict__ im,
                                            int kp, float2 U, float& pp, float& pm) {
  const int k1 = kp & (NC - 1);
  const int k2 = (NC - kp) & (NC - 1);
  const int q1 = SW(posrev10(k1 & 1023));
  const int q2 = SW(posrev10(k2 & 1023));
  const float s1 = (k1 & 1024) ? -1.0f : 1.0f;
  const float s2 = (k2 & 1024) ? -1.0f : 1.0f;
  const float zkr = re[q1] + s1 * re[q1 ^ 1];
  const float zki = im[q1] + s1 * im[q1 ^ 1];
  const float zmr = re[q2] + s2 * re[q2 ^ 1];
  const float zmi = im[q2] + s2 * im[q2 ^ 1];
  const float Ex = 0.5f * (zkr + zmr), Ey = 0.5f * (zki - zmi);
  const float Ox = 0.5f * (zki + zmi), Oy = -0.5f * (zkr - zmr);
  const float Vx = U.x * Ox - U.y * Oy, Vy = U.x * Oy + U.y * Ox;
  const float ax = Ex + Vx, ay = Ey + Vy;
  const float bx = Ex - Vx, by = Ey - Vy;
  pp = ax * ax + ay * ay;
  pm = bx * bx + by * by;
}

// ACT: 0 s1a=min(p,1e6); 1 s1b=min(p,1e6); 2 lvl0 fold into s1a&s1b;
//      3 s2a=min(s1a,p); 4 s2b=min(s1a,p); 5 s2a=min(s1b,p); 6 s2b=min(s1b,p);
//      7 o[COL]=dB(min(s2a,p)); 8 o[COL]=dB(min(s2b,p))
template <int ACT, int COL, int SLOT>
__device__ __forceinline__ void act(State& st, float p) {
  if constexpr (ACT == 0)      st.s1a[SLOT] = fminf(p, 1.0e6f);
  else if constexpr (ACT == 1) st.s1b[SLOT] = fminf(p, 1.0e6f);
  else if constexpr (ACT == 2) { st.s1a[SLOT] = fminf(st.s1a[SLOT], p); st.s1b[SLOT] = fminf(st.s1b[SLOT], p); }
  else if constexpr (ACT == 3) st.s2a[SLOT] = fminf(st.s1a[SLOT], p);
  else if constexpr (ACT == 4) st.s2b[SLOT] = fminf(st.s1a[SLOT], p);
  else if constexpr (ACT == 5) st.s2a[SLOT] = fminf(st.s1b[SLOT], p);
  else if constexpr (ACT == 6) st.s2b[SLOT] = fminf(st.s1b[SLOT], p);
  else if constexpr (ACT == 7) st.o[COL][SLOT] = 10.0f * log10f(fmaxf(fminf(st.s2a[SLOT], p), 1.0e-10f));
  else                         st.o[COL][SLOT] = 10.0f * log10f(fmaxf(fminf(st.s2b[SLOT], p), 1.0e-10f));
}

template <int ACT, int COL>
__device__ __forceinline__ void unpack_frame(const float* __restrict__ re,
                                             const float* __restrict__ im,
                                             State& st) {
  const int t = threadIdx.x;
  float pp, pm;
  pair_powers(re, im, t, st.Ub, pp, pm);
  act<ACT, COL, 0>(st, pp);
  act<ACT, COL, 1>(st, pm);
  pair_powers(re, im, 512 + t, st.U1, pp, pm);
  act<ACT, COL, 2>(st, pp);
  act<ACT, COL, 3>(st, pm);
  if (t == 0) {
    // bin 1024: Z[1024] = D[0] - D[1]
    const float zr = re[0] - re[1];
    const float zi = im[0] - im[1];
    act<ACT, COL, 4>(st, zr * zr + zi * zi);
  }
}

// One pass = two windowed frames, FFT'd together, unpacked, min-chain applied.
template <int LA, int ACTA, int COLA, int LB, int ACTB, int COLB, bool HASB>
__device__ __forceinline__ void pass(Smem& sm, State& st, int offA, int offB) {
  __syncthreads();                          // prior pass done reading z arrays
  fused_s1<LA>(sm.zreA, sm.zimA, sm, st, offA);
  if constexpr (HASB) fused_s1<LB>(sm.zreB, sm.zimB, sm, st, offB);
  __syncthreads(); radix4p<7, HASB>(sm, st.W[1]);
  __syncthreads(); radix4p<5, HASB>(sm, st.W[2]);
  __syncthreads(); radix4p<3, HASB>(sm, st.W[3]);
  __syncthreads(); radix4p<1, HASB>(sm, st.W[4]);
  __syncthreads();
  unpack_frame<ACTA, COLA>(sm.zreA, sm.zimA, st);
  if constexpr (HASB) unpack_frame<ACTB, COLB>(sm.zreB, sm.zimB, st);
}

// Fused final store: thread t owns bands {t, 2048-t, 512+t, 1536-t, (1024 if t==0)}
// across ALL passes, so all 8 columns of those bands are in registers; write
// 32 contiguous bytes per band (two adjacent float4s).
__device__ __forceinline__ void store_all(const State& st, float* __restrict__ outb) {
  const int t = threadIdx.x;
  #pragma unroll
  for (int sl = 0; sl < 5; ++sl) {
    if (sl < 4 || t == 0) {
      const int band = (sl == 0) ? t : (sl == 1) ? 2048 - t
                     : (sl == 2) ? 512 + t : (sl == 3) ? 1536 - t : 1024;
      float* bp = outb + (size_t)band * 8;
      *(float4*)(bp)     = make_float4(st.o[0][sl], st.o[1][sl], st.o[2][sl], st.o[3][sl]);
      *(float4*)(bp + 4) = make_float4(st.o[4][sl], st.o[5][sl], st.o[6][sl], st.o[7][sl]);
    }
  }
}

__global__ __launch_bounds__(THREADS, 2) void spec_kernel(const float* __restrict__ x,
                                                          float* __restrict__ out) {
  __shared__ Smem sm;
  State st;
  const int tid = threadIdx.x;
  const int b = blockIdx.x;
  const float* xb = x + (size_t)b * BUF;
  #pragma unroll
  for (int i = tid; i < BUF; i += THREADS) sm.xs[i] = xb[i];
  {
    float sn, cs;
    sincospif((float)tid * (1.0f / 1024.0f), &sn, &cs);         st.W[0] = make_float2(cs, -sn);
    sincospif((float)(tid & 127) * (1.0f / 256.0f), &sn, &cs);  st.W[1] = make_float2(cs, -sn);
    sincospif((float)(tid & 31) * (1.0f / 64.0f), &sn, &cs);    st.W[2] = make_float2(cs, -sn);
    sincospif((float)(tid & 7) * (1.0f / 16.0f), &sn, &cs);     st.W[3] = make_float2(cs, -sn);
    st.W[4] = (tid & 1) ? make_float2(R2C, -R2C) : make_float2(1.0f, 0.0f);
    sincospif((float)tid * (1.0f / 2048.0f), &sn, &cs);         st.Ub = make_float2(cs, -sn);
    st.U1 = cmul(st.Ub, make_float2(R2C, -R2C));
    sincospif((float)(2 * tid + 1) * (1.0f / 2048.0f), &sn, &cs); st.so = sn;
  }
  float* outb = out + (size_t)b * (NBANDS * 8);

  // Frames: lvl0 off=1024; lvl1 off=512*(i+1); lvl2 off=256*(i+1); lvl3 off=128*(i+1)
  pass<1, 0, 0,  1, 1, 0, true >(sm, st, 512, 1024);   // s1a=l1_0, s1b=l1_1
  pass<0, 2, 0,  2, 3, 0, true >(sm, st, 1024, 256);   // fold lvl0; s2a=min(s1a,l2_0)
  pass<2, 4, 0,  3, 7, 0, true >(sm, st, 512, 128);    // s2b=min(s1a,l2_1); o0=dB(s2a,l3_0)
  pass<3, 7, 1,  3, 8, 2, true >(sm, st, 256, 384);    // o1=dB(s2a,l3_1); o2=dB(s2b,l3_2)
  pass<3, 8, 3,  2, 5, 0, true >(sm, st, 512, 768);    // o3=dB(s2b,l3_3); s2a=min(s1b,l2_2)
  pass<2, 6, 0,  3, 7, 4, true >(sm, st, 1024, 640);   // s2b=min(s1b,l2_3); o4=dB(s2a,l3_4)
  pass<3, 7, 5,  3, 8, 6, true >(sm, st, 768, 896);    // o5=dB(s2a,l3_5); o6=dB(s2b,l3_6)
  pass<3, 8, 7,  0, 0, 0, false>(sm, st, 1024, 0);     // o7=dB(s2b,l3_7)
  store_all(st, outb);
}

extern "C" void kernel_launch(void* const* d_in, const int* in_sizes, int n_in,
                              void* d_out, int out_size, void* d_ws, size_t ws_size,
                              hipStream_t stream) {
  const float* x = (const float*)d_in[0];
  float* out = (float*)d_out;
  const int B = in_sizes[0] / BUF;
  hipLaunchKernelGGL(spec_kernel, dim3(B), dim3(THREADS), 0, stream, x, out);
}

// Round 9
// 96.902 us; speedup vs baseline: 1.1517x; 1.0380x over previous
//
#include <hip/hip_runtime.h>
#include <hip/hip_fp16.h>
#include <math.h>

#define NBANDS 2049
#define NF 4096      // real frame size
#define NC 2048      // complex FFT size (rfft via packed complex)
#define BUF 1024     // input samples per batch row
#define THREADS 512
#define R2C 0.70710678118654752f

// LDS bank swizzle: bijective on [0,2048); SW(e^1) == SW(e)^1
__device__ __forceinline__ int SW(int i) { return i ^ (i >> 2) ^ (i >> 6); }

// digit-reversed position after 5 radix-4 stages (final radix-2 folded out);
// output is always even
__device__ __forceinline__ int posrev10(int j) {
  return ((j & 3) << 9) | (((j >> 2) & 3) << 7) | (((j >> 4) & 3) << 5) |
         (((j >> 6) & 3) << 3) | (((j >> 8) & 3) << 1);
}

struct Smem {
  alignas(16) float xs[BUF];                 // 4 KB
  alignas(16) float zreA[NC];                // 8 KB each
  alignas(16) float zimA[NC];
  alignas(16) float zreB[NC];
  alignas(16) float zimB[NC];
  alignas(16) float zreC[NC];
  alignas(16) float zimC[NC];
};                                           // 52.5 KB -> 2 blocks/CU

struct State {
  float2 W[5];                   // per-thread stage twiddles
  float2 Ub;                     // exp(-pi*i*tid/2048)
  float2 U1;                     // Ub * exp(-i*pi/4)
  float so;                      // sin(pi*(2*tid+1)/2048) (odd window base)
  float s1a[5], s1b[5];          // running mins after lvl1 (two subtrees)
  float s2a[5], s2b[5];          // running mins after lvl2 (two live nodes)
  __half2 oh[4][5];              // dB output columns, f16-packed in registers
};

__device__ __forceinline__ float2 cmul(float2 a, float2 b) {
  return make_float2(a.x * b.x - a.y * b.y, a.x * b.y + a.y * b.x);
}

// Chebyshev cos-doubling: cos(t) -> cos(2^L * t)
template <int L>
__device__ __forceinline__ float cheb(float c) {
  #pragma unroll
  for (int i = 0; i < L; ++i) c = 2.0f * c * c - 1.0f;
  return c;
}

// Fused pack + pruned first radix-4 stage (span 512): only tap3 nonzero.
// y = {d, i*d*W, -d*W^2, -i*d*W^3}, d = windowed sample pair from xs.
template <int L>
__device__ __forceinline__ void fused_s1(float* __restrict__ re, float* __restrict__ im,
                                         const Smem& sm, const State& st, int off) {
  const int n = threadIdx.x;
  constexpr int M = NF >> L;
  constexpr float ws = (float)(1 << L) * (0.5f / 1024.0f);
  const int lo = 512 - (min(off, M) >> 1);
  float dr = 0.0f, di = 0.0f;
  if (n >= lo) {
    const int idx = 2 * n + off - 1024;          // even, in [0, off)
    const float2 xv = *(const float2*)&sm.xs[idx];
    const float cE = cheb<L>(-st.W[0].y);        // cos at even sample
    const float cO = cheb<L>(st.so);             // cos at odd sample
    dr = ws * (1.0f - cE) * xv.x;
    di = ws * (1.0f - cO) * xv.y;
  }
  const float2 W = st.W[0];
  const float2 W2 = make_float2(W.x * W.x - W.y * W.y, 2.0f * W.x * W.y);
  const float2 W3 = cmul(W, W2);
  const int p0 = SW(n), p1 = SW(n + 512), p2 = SW(n + 1024), p3 = SW(n + 1536);
  re[p0] = dr;                       im[p0] = di;
  re[p1] = -di * W.x - dr * W.y;     im[p1] = -di * W.y + dr * W.x;     // (i d) W
  re[p2] = -(dr * W2.x - di * W2.y); im[p2] = -(dr * W2.y + di * W2.x); // -d W^2
  re[p3] =  di * W3.x + dr * W3.y;   im[p3] =  di * W3.y - dr * W3.x;   // (-i d) W^3
}

__device__ __forceinline__ void bfly4(float* __restrict__ re, float* __restrict__ im,
                                      int i0, int i1, int i2, int i3,
                                      float2 W, float2 W2, float2 W3) {
  float ar = re[i0], ai = im[i0];
  float br = re[i1], bi = im[i1];
  float cr = re[i2], ci = im[i2];
  float dr = re[i3], di = im[i3];
  float t0r = ar + cr, t0i = ai + ci;
  float t1r = ar - cr, t1i = ai - ci;
  float t2r = br + dr, t2i = bi + di;
  float t3r = br - dr, t3i = bi - di;
  re[i0] = t0r + t2r; im[i0] = t0i + t2i;
  float y1r = t1r + t3i, y1i = t1i - t3r;                  // (t1 - i*t3)
  re[i1] = y1r * W.x - y1i * W.y;  im[i1] = y1r * W.y + y1i * W.x;
  float y2r = t0r - t2r, y2i = t0i - t2i;
  re[i2] = y2r * W2.x - y2i * W2.y; im[i2] = y2r * W2.y + y2i * W2.x;
  float y3r = t1r - t3i, y3i = t1i + t3r;                  // (t1 + i*t3)
  re[i3] = y3r * W3.x - y3i * W3.y; im[i3] = y3r * W3.y + y3i * W3.x;
}

template <int LM, int NFR>
__device__ __forceinline__ void radix4p(Smem& sm, float2 W) {
  const int j = threadIdx.x;
  const int m = 1 << LM;
  const int base = ((j >> LM) << (LM + 2)) | (j & (m - 1));
  const int i0 = SW(base), i1 = SW(base + m), i2 = SW(base + 2 * m), i3 = SW(base + 3 * m);
  float2 W2 = make_float2(W.x * W.x - W.y * W.y, 2.0f * W.x * W.y);
  float2 W3 = cmul(W, W2);
  bfly4(sm.zreA, sm.zimA, i0, i1, i2, i3, W, W2, W3);
  if constexpr (NFR >= 2) bfly4(sm.zreB, sm.zimB, i0, i1, i2, i3, W, W2, W3);
  if constexpr (NFR >= 3) bfly4(sm.zreC, sm.zimC, i0, i1, i2, i3, W, W2, W3);
}

// Shared-read pair unpack: bins kp and 2048-kp read the same Z values.
// {q, q^1} is an adjacent aligned float pair -> one b64 LDS read each.
// p(kp) = |E + U*O|^2, p(2048-kp) = |E - U*O|^2.
__device__ __forceinline__ void pair_powers(const float* __restrict__ re,
                                            const float* __restrict__ im,
                                            int kp, float2 U, float& pp, float& pm) {
  const int k1 = kp & (NC - 1);
  const int k2 = (NC - kp) & (NC - 1);
  const int q1 = SW(posrev10(k1 & 1023));
  const int q2 = SW(posrev10(k2 & 1023));
  const float s1 = (k1 & 1024) ? -1.0f : 1.0f;
  const float s2 = (k2 & 1024) ? -1.0f : 1.0f;
  const float2 vr1 = *(const float2*)&re[q1 & ~1];
  const float2 vi1 = *(const float2*)&im[q1 & ~1];
  const float2 vr2 = *(const float2*)&re[q2 & ~1];
  const float2 vi2 = *(const float2*)&im[q2 & ~1];
  const bool o1 = (q1 & 1), o2 = (q2 & 1);
  const float zkr = o1 ? (vr1.y + s1 * vr1.x) : (vr1.x + s1 * vr1.y);
  const float zki = o1 ? (vi1.y + s1 * vi1.x) : (vi1.x + s1 * vi1.y);
  const float zmr = o2 ? (vr2.y + s2 * vr2.x) : (vr2.x + s2 * vr2.y);
  const float zmi = o2 ? (vi2.y + s2 * vi2.x) : (vi2.x + s2 * vi2.y);
  const float Ex = 0.5f * (zkr + zmr), Ey = 0.5f * (zki - zmi);
  const float Ox = 0.5f * (zki + zmi), Oy = -0.5f * (zkr - zmr);
  const float Vx = U.x * Ox - U.y * Oy, Vy = U.x * Oy + U.y * Ox;
  const float ax = Ex + Vx, ay = Ey + Vy;
  const float bx = Ex - Vx, by = Ey - Vy;
  pp = ax * ax + ay * ay;
  pm = bx * bx + by * by;
}

// ACT: 0 s1a=min(p,1e6); 1 s1b=min(p,1e6); 2 lvl0 fold into s1a&s1b;
//      3 s2a=min(s1a,p); 4 s2b=min(s1a,p); 5 s2a=min(s1b,p); 6 s2b=min(s1b,p);
//      7 o[COL]=dB(min(s2a,p)); 8 o[COL]=dB(min(s2b,p))
template <int ACT, int COL, int SLOT>
__device__ __forceinline__ void act(State& st, float p) {
  if constexpr (ACT == 0)      st.s1a[SLOT] = fminf(p, 1.0e6f);
  else if constexpr (ACT == 1) st.s1b[SLOT] = fminf(p, 1.0e6f);
  else if constexpr (ACT == 2) { st.s1a[SLOT] = fminf(st.s1a[SLOT], p); st.s1b[SLOT] = fminf(st.s1b[SLOT], p); }
  else if constexpr (ACT == 3) st.s2a[SLOT] = fminf(st.s1a[SLOT], p);
  else if constexpr (ACT == 4) st.s2b[SLOT] = fminf(st.s1a[SLOT], p);
  else if constexpr (ACT == 5) st.s2a[SLOT] = fminf(st.s1b[SLOT], p);
  else if constexpr (ACT == 6) st.s2b[SLOT] = fminf(st.s1b[SLOT], p);
  else {
    const float base = (ACT == 7) ? st.s2a[SLOT] : st.s2b[SLOT];
    const float db = 10.0f * log10f(fmaxf(fminf(base, p), 1.0e-10f));
    if constexpr (COL & 1) st.oh[COL >> 1][SLOT].y = __float2half_rn(db);
    else                   st.oh[COL >> 1][SLOT].x = __float2half_rn(db);
  }
}

template <int ACT, int COL>
__device__ __forceinline__ void unpack_frame(const float* __restrict__ re,
                                             const float* __restrict__ im,
                                             State& st) {
  const int t = threadIdx.x;
  float pp, pm;
  pair_powers(re, im, t, st.Ub, pp, pm);
  act<ACT, COL, 0>(st, pp);
  act<ACT, COL, 1>(st, pm);
  pair_powers(re, im, 512 + t, st.U1, pp, pm);
  act<ACT, COL, 2>(st, pp);
  act<ACT, COL, 3>(st, pm);
  if (t == 0) {
    // bin 1024: Z[1024] = D[0] - D[1]
    const float zr = re[0] - re[1];
    const float zi = im[0] - im[1];
    act<ACT, COL, 4>(st, zr * zr + zi * zi);
  }
}

// One pass = three windowed frames FFT'd together, unpacked, min-chain applied.
template <int LA, int AA, int CA, int LB, int AB, int CB, int LC, int AC, int CC, int NFR>
__device__ __forceinline__ void pass(Smem& sm, State& st, int offA, int offB, int offC) {
  __syncthreads();                          // prior pass done reading z arrays
  fused_s1<LA>(sm.zreA, sm.zimA, sm, st, offA);
  if constexpr (NFR >= 2) fused_s1<LB>(sm.zreB, sm.zimB, sm, st, offB);
  if constexpr (NFR >= 3) fused_s1<LC>(sm.zreC, sm.zimC, sm, st, offC);
  __syncthreads(); radix4p<7, NFR>(sm, st.W[1]);
  __syncthreads(); radix4p<5, NFR>(sm, st.W[2]);
  __syncthreads(); radix4p<3, NFR>(sm, st.W[3]);
  __syncthreads(); radix4p<1, NFR>(sm, st.W[4]);
  __syncthreads();
  unpack_frame<AA, CA>(sm.zreA, sm.zimA, st);
  if constexpr (NFR >= 2) unpack_frame<AB, CB>(sm.zreB, sm.zimB, st);
  if constexpr (NFR >= 3) unpack_frame<AC, CC>(sm.zreC, sm.zimC, st);
}

// Fused final store: thread t owns bands {t, 2048-t, 512+t, 1536-t, (1024 if t==0)}
// across ALL passes; write 32 contiguous bytes per band (two float4s).
__device__ __forceinline__ void store_all(const State& st, float* __restrict__ outb) {
  const int t = threadIdx.x;
  #pragma unroll
  for (int sl = 0; sl < 5; ++sl) {
    if (sl < 4 || t == 0) {
      const int band = (sl == 0) ? t : (sl == 1) ? 2048 - t
                     : (sl == 2) ? 512 + t : (sl == 3) ? 1536 - t : 1024;
      float* bp = outb + (size_t)band * 8;
      *(float4*)(bp)     = make_float4(__half2float(st.oh[0][sl].x), __half2float(st.oh[0][sl].y),
                                       __half2float(st.oh[1][sl].x), __half2float(st.oh[1][sl].y));
      *(float4*)(bp + 4) = make_float4(__half2float(st.oh[2][sl].x), __half2float(st.oh[2][sl].y),
                                       __half2float(st.oh[3][sl].x), __half2float(st.oh[3][sl].y));
    }
  }
}

__global__ __launch_bounds__(THREADS, 2) void spec_kernel(const float* __restrict__ x,
                                                          float* __restrict__ out) {
  __shared__ Smem sm;
  State st;
  const int tid = threadIdx.x;
  const int b = blockIdx.x;
  const float* xb = x + (size_t)b * BUF;
  #pragma unroll
  for (int i = tid; i < BUF; i += THREADS) sm.xs[i] = xb[i];
  {
    float sn, cs;
    sincospif((float)tid * (1.0f / 1024.0f), &sn, &cs);         st.W[0] = make_float2(cs, -sn);
    sincospif((float)(tid & 127) * (1.0f / 256.0f), &sn, &cs);  st.W[1] = make_float2(cs, -sn);
    sincospif((float)(tid & 31) * (1.0f / 64.0f), &sn, &cs);    st.W[2] = make_float2(cs, -sn);
    sincospif((float)(tid & 7) * (1.0f / 16.0f), &sn, &cs);     st.W[3] = make_float2(cs, -sn);
    st.W[4] = (tid & 1) ? make_float2(R2C, -R2C) : make_float2(1.0f, 0.0f);
    sincospif((float)tid * (1.0f / 2048.0f), &sn, &cs);         st.Ub = make_float2(cs, -sn);
    st.U1 = cmul(st.Ub, make_float2(R2C, -R2C));
    sincospif((float)(2 * tid + 1) * (1.0f / 2048.0f), &sn, &cs); st.so = sn;
  }
  float* outb = out + (size_t)b * (NBANDS * 8);

  // Frames: lvl0 off=1024; lvl1 off=512*(i+1); lvl2 off=256*(i+1); lvl3 off=128*(i+1)
  // 15 frames in 5 passes of 3:
  pass<1, 0, 0,  1, 1, 0,  0, 2, 0, 3>(sm, st, 512, 1024, 1024);  // s1a=l1_0; s1b=l1_1; fold l0
  pass<2, 3, 0,  2, 4, 0,  3, 7, 0, 3>(sm, st, 256, 512, 128);    // s2a=min(s1a,l2_0); s2b=min(s1a,l2_1); o0
  pass<3, 7, 1,  3, 8, 2,  3, 8, 3, 3>(sm, st, 256, 384, 512);    // o1(s2a); o2(s2b); o3(s2b)
  pass<2, 5, 0,  2, 6, 0,  3, 7, 4, 3>(sm, st, 768, 1024, 640);   // s2a=min(s1b,l2_2); s2b=min(s1b,l2_3); o4
  pass<3, 7, 5,  3, 8, 6,  3, 8, 7, 3>(sm, st, 768, 896, 1024);   // o5(s2a); o6(s2b); o7(s2b)
  store_all(st, outb);
}

extern "C" void kernel_launch(void* const* d_in, const int* in_sizes, int n_in,
                              void* d_out, int out_size, void* d_ws, size_t ws_size,
                              hipStream_t stream) {
  const float* x = (const float*)d_in[0];
  float* out = (float*)d_out;
  const int B = in_sizes[0] / BUF;
  hipLaunchKernelGGL(spec_kernel, dim3(B), dim3(THREADS), 0, stream, x, out);
}